// Round 11
// baseline (211.734 us; speedup 1.0000x reference)
//
#include <hip/hip_runtime.h>
#include <hip/hip_fp16.h>

#define DIN 128
#define BSH 7                 // log2(targets per bucket)
#define BSIZE 128             // targets per bucket (place granularity)
#define HB 64                 // targets per half-bucket (gather granularity)
#define NBMAX 800             // max bucket count
#define NBMAX2 1600           // max half-bucket count
#define CAP 4480              // slots per bucket region (mean 4096 + 6 sigma)
#define HCAP 2560             // slots per half-bucket srt2 region (mean 2048 + 11 sigma)
#define CHUNK 8192            // edges per place-WG
#define PB 512                // place block size

// ---------- K1: bucket the edges (LDS-staged, coalesced run writes) ----------
__global__ __launch_bounds__(PB) void place_kernel(const int* __restrict__ row,
                                                   const int* __restrict__ col,
                                                   int* __restrict__ cur,
                                                   int* __restrict__ sp, int E, int NB) {
    __shared__ int pk[CHUNK];
    __shared__ unsigned short bkid[CHUNK];
    __shared__ int lcnt[NBMAX], lstart[NBMAX], gofs[NBMAX], lcur[NBMAX];
    __shared__ int sst[PB];
    int t = threadIdx.x;
    int e0 = blockIdx.x * CHUNK;
    int cnt = min(CHUNK, E - e0);

    for (int i = t; i < NBMAX; i += PB) { lcnt[i] = 0; lcur[i] = 0; }
    __syncthreads();
    for (int i = t; i < cnt; i += PB)
        atomicAdd(&lcnt[col[e0 + i] >> BSH], 1);
    __syncthreads();
    int b2i = t * 2;
    int v0 = (b2i + 0 < NBMAX) ? lcnt[b2i + 0] : 0;
    int v1 = (b2i + 1 < NBMAX) ? lcnt[b2i + 1] : 0;
    int tot = v0 + v1;
    sst[t] = tot;
    __syncthreads();
    for (int d = 1; d < PB; d <<= 1) {
        int tmp = (t >= d) ? sst[t - d] : 0;
        __syncthreads();
        sst[t] += tmp;
        __syncthreads();
    }
    int ex = sst[t] - tot;
    if (b2i + 0 < NBMAX) lstart[b2i + 0] = ex;
    if (b2i + 1 < NBMAX) lstart[b2i + 1] = ex + v0;
    __syncthreads();
    for (int b = t; b < NB; b += PB) {
        int c = lcnt[b];
        int gb = c ? atomicAdd(&cur[b], c) : 0;
        gofs[b] = b * CAP + gb - lstart[b];
    }
    __syncthreads();
    for (int i = t; i < cnt; i += PB) {
        int r  = row[e0 + i];
        int cc = col[e0 + i];
        int b  = cc >> BSH;
        int rk = atomicAdd(&lcur[b], 1);
        int pos = lstart[b] + rk;
        pk[pos]   = ((cc & (BSIZE - 1)) << 17) | r;
        bkid[pos] = (unsigned short)b;
    }
    __syncthreads();
    for (int i = t; i < cnt; i += PB)
        sp[gofs[bkid[i]] + i] = pk[i];
}

// ---------- K2: fused per-half-bucket degree + (x @ W1) * dis -> hp, dis ----------
// block i handles nodes [64i, 64i+64) == bucket i>>1, half i&1.
__global__ __launch_bounds__(256) void xw1_kernel(const float* __restrict__ x,
                                                  const float* __restrict__ W1,
                                                  const int* __restrict__ sp,
                                                  const int* __restrict__ cur,
                                                  float* __restrict__ dis,
                                                  __half* __restrict__ hp, int N) {
    __shared__ float xs[64 * 132];
    __shared__ float wt[16 * 132];
    __shared__ int   lcnt[HB];
    __shared__ float disl[HB];
    int t = threadIdx.x;
    int blk = blockIdx.x;
    int base = blk * 64;
    int B = blk >> 1, h = blk & 1;
    if (t < HB) lcnt[t] = 0;
    for (int i = t; i < DIN * 16; i += 256) {
        int d = i >> 4, k = i & 15;
        wt[k * 132 + d] = W1[i];
    }
    int nrow = min(64, N - base);
    for (int i = t; i < 64 * 32; i += 256) {
        int r = i >> 5, c4 = i & 31;
        float4 v = make_float4(0.f, 0.f, 0.f, 0.f);
        if (r < nrow) v = *(const float4*)(x + (size_t)(base + r) * DIN + c4 * 4);
        *(float4*)(xs + r * 132 + c4 * 4) = v;
    }
    __syncthreads();
    // degree count for this half-bucket
    int cntb = cur[B];
    const int* reg = sp + (size_t)B * CAP;
    for (int i = t; i < cntb; i += 256) {
        int lc = reg[i] >> 17;
        if ((lc >> 6) == h) atomicAdd(&lcnt[lc & 63], 1);
    }
    __syncthreads();
    if (t < HB) {
        float dv = rsqrtf((float)lcnt[t] + 1.0f);
        disl[t] = dv;
        int gt = base + t;
        if (gt < N) dis[gt] = dv;
    }
    __syncthreads();
    // 2x2 blocked matmul
    int np = t >> 3;
    int kp = t & 7;
    int n0 = np * 2, k0 = kp * 2;
    const float4* xa = (const float4*)(xs + n0 * 132);
    const float4* xb = (const float4*)(xs + (n0 + 1) * 132);
    const float4* wa = (const float4*)(wt + k0 * 132);
    const float4* wb = (const float4*)(wt + (k0 + 1) * 132);
    float a00 = 0.f, a01 = 0.f, a10 = 0.f, a11 = 0.f;
    #pragma unroll 8
    for (int d4 = 0; d4 < 32; d4++) {
        float4 va = xa[d4], vb = xb[d4], u0 = wa[d4], u1 = wb[d4];
        a00 += va.x*u0.x + va.y*u0.y + va.z*u0.z + va.w*u0.w;
        a01 += va.x*u1.x + va.y*u1.y + va.z*u1.z + va.w*u1.w;
        a10 += vb.x*u0.x + vb.y*u0.y + vb.z*u0.z + vb.w*u0.w;
        a11 += vb.x*u1.x + vb.y*u1.y + vb.z*u1.z + vb.w*u1.w;
    }
    int n = base + n0;
    if (n < N) {
        float d = disl[n0];
        hp[(size_t)n * 16 + k0 + 0] = __float2half(a00 * d);
        hp[(size_t)n * 16 + k0 + 1] = __float2half(a01 * d);
    }
    n++;
    if (n < N) {
        float d = disl[n0 + 1];
        hp[(size_t)n * 16 + k0 + 0] = __float2half(a10 * d);
        hp[(size_t)n * 16 + k0 + 1] = __float2half(a11 * d);
    }
}

// ---------- K3: per-half-bucket sort + gather1 + relu/b1/@W2/*dis -> gp, srt2, off ----------
__global__ __launch_bounds__(256) void bsg1_kernel(const int* __restrict__ sp,
                                                   const int* __restrict__ cur,
                                                   const float* __restrict__ dis,
                                                   const __half2* __restrict__ hp2,
                                                   const float* __restrict__ b1,
                                                   const float* __restrict__ W2,
                                                   int* __restrict__ srt2,
                                                   int* __restrict__ off,
                                                   float* __restrict__ gp, int N) {
    __shared__ int ss[HCAP];
    __shared__ int lcnt[HB], lstart[HB], lcur[HB], sc[HB];
    int b2 = blockIdx.x;
    int B = b2 >> 1, h = b2 & 1;
    int t = threadIdx.x;
    int cntb = cur[B];
    const int* reg = sp + (size_t)B * CAP;
    if (t < HB) { lcnt[t] = 0; lcur[t] = 0; }
    __syncthreads();
    // pass 1: count this half's targets
    for (int i = t; i < cntb; i += 256) {
        int lc = reg[i] >> 17;
        if ((lc >> 6) == h) atomicAdd(&lcnt[lc & 63], 1);
    }
    __syncthreads();
    int v = (t < HB) ? lcnt[t] : 0;
    if (t < HB) sc[t] = v;
    __syncthreads();
    for (int d = 1; d < HB; d <<= 1) {
        int tmp = (t < HB && t >= d) ? sc[t - d] : 0;
        __syncthreads();
        if (t < HB) sc[t] += tmp;
        __syncthreads();
    }
    if (t < HB) lstart[t] = sc[t] - v;
    __syncthreads();
    // pass 2: place (region is L2-hot from pass 1)
    for (int i = t; i < cntb; i += 256) {
        int vv = reg[i];
        int lc = vv >> 17;
        if ((lc >> 6) == h) {
            int l = lc & 63;
            int rk = atomicAdd(&lcur[l], 1);
            ss[lstart[l] + rk] = vv & 0x1FFFF;
        }
    }
    __syncthreads();
    int hcnt = sc[HB - 1];
    // write back sorted half + off (coalesced)
    for (int i = t; i < hcnt; i += 256) srt2[(size_t)b2 * HCAP + i] = ss[i];
    if (t < HB) {
        off[b2 * (HB + 1) + t] = b2 * HCAP + lstart[t];
    } else if (t == HB) {
        off[b2 * (HB + 1) + HB] = b2 * HCAP + hcnt;
    }
    // gather + epilogue: 2 rounds of 32 targets x 8 lanes; 4-way ILP
    int k2  = t & 7;
    int ltg = t >> 3;
    #pragma unroll
    for (int r2 = 0; r2 < 2; r2++) {
        int lt = r2 * 32 + ltg;
        int gt = B * BSIZE + h * HB + lt;
        if (gt < N) {
            int j0 = lstart[lt];
            int j1 = j0 + lcnt[lt];
            float2 acc0 = __half22float2(hp2[(size_t)gt * 8 + k2]);  // self-loop
            float2 acc1 = make_float2(0.f, 0.f);
            float2 acc2 = make_float2(0.f, 0.f);
            float2 acc3 = make_float2(0.f, 0.f);
            int j = j0;
            for (; j + 3 < j1; j += 4) {
                int r0 = ss[j + 0], r1 = ss[j + 1], r2i = ss[j + 2], r3 = ss[j + 3];
                float2 h0 = __half22float2(hp2[(size_t)r0 * 8 + k2]);
                float2 h1 = __half22float2(hp2[(size_t)r1 * 8 + k2]);
                float2 h2 = __half22float2(hp2[(size_t)r2i * 8 + k2]);
                float2 h3 = __half22float2(hp2[(size_t)r3 * 8 + k2]);
                acc0.x += h0.x; acc0.y += h0.y;
                acc1.x += h1.x; acc1.y += h1.y;
                acc2.x += h2.x; acc2.y += h2.y;
                acc3.x += h3.x; acc3.y += h3.y;
            }
            for (; j < j1; j++) {
                int r = ss[j];
                float2 hv = __half22float2(hp2[(size_t)r * 8 + k2]);
                acc0.x += hv.x; acc0.y += hv.y;
            }
            float2 acc = make_float2(acc0.x + acc1.x + acc2.x + acc3.x,
                                     acc0.y + acc1.y + acc2.y + acc3.y);
            float d = dis[gt];
            int k0 = k2 * 2;
            float v0 = fmaxf(fmaf(acc.x, d, b1[k0 + 0]), 0.0f);
            float v1 = fmaxf(fmaf(acc.y, d, b1[k0 + 1]), 0.0f);
            float p0 = v0 * W2[k0 * 2 + 0] + v1 * W2[k0 * 2 + 2];
            float p1 = v0 * W2[k0 * 2 + 1] + v1 * W2[k0 * 2 + 3];
            p0 += __shfl_xor(p0, 1); p1 += __shfl_xor(p1, 1);
            p0 += __shfl_xor(p0, 2); p1 += __shfl_xor(p1, 2);
            p0 += __shfl_xor(p0, 4); p1 += __shfl_xor(p1, 4);
            if (k2 == 0) *(float2*)(gp + (size_t)gt * 2) = make_float2(p0 * d, p1 * d);
        }
    }
}

// ---------- K4: gather-2 over srt2 (8 lanes/target) + bias + log_softmax ----------
__global__ __launch_bounds__(256) void g2_kernel(const int* __restrict__ srt2,
                                                 const int* __restrict__ off,
                                                 const float* __restrict__ dis,
                                                 const float* __restrict__ gp,
                                                 const float* __restrict__ b2,
                                                 float* __restrict__ out, int N) {
    int t = blockIdx.x * 256 + threadIdx.x;
    int c    = t >> 3;
    int slot = t & 7;
    if (c >= N) return;
    int idx = (c >> 6) * (HB + 1) + (c & 63);
    int j0 = off[idx];
    int j1 = off[idx + 1];
    float a0 = 0.0f, a1v = 0.0f;
    for (int j = j0 + slot; j < j1; j += 8) {
        int r = srt2[j];
        float2 gv = *(const float2*)(gp + (size_t)r * 2);
        a0  += gv.x;
        a1v += gv.y;
    }
    a0 += __shfl_xor(a0, 1); a1v += __shfl_xor(a1v, 1);
    a0 += __shfl_xor(a0, 2); a1v += __shfl_xor(a1v, 2);
    a0 += __shfl_xor(a0, 4); a1v += __shfl_xor(a1v, 4);
    if (slot == 0) {
        float2 self = *(const float2*)(gp + (size_t)c * 2);
        float d = dis[c];
        float o0 = (a0  + self.x) * d + b2[0];
        float o1 = (a1v + self.y) * d + b2[1];
        float m = fmaxf(o0, o1);
        float lse = m + logf(expf(o0 - m) + expf(o1 - m));
        *(float2*)(out + (size_t)c * 2) = make_float2(o0 - lse, o1 - lse);
    }
}

extern "C" void kernel_launch(void* const* d_in, const int* in_sizes, int n_in,
                              void* d_out, int out_size, void* d_ws, size_t ws_size,
                              hipStream_t stream) {
    const float* x  = (const float*)d_in[0];
    const int*   ei = (const int*)d_in[1];
    const float* W1 = (const float*)d_in[2];
    const float* b1 = (const float*)d_in[3];
    const float* W2 = (const float*)d_in[4];
    const float* b2 = (const float*)d_in[5];
    float* out = (float*)d_out;

    const int N = in_sizes[0] / DIN;          // 100000
    const int E = in_sizes[1] / 2;            // 3200000
    const int* row = ei;                      // sources
    const int* col = ei + E;                  // targets
    const int NB  = (N + BSIZE - 1) / BSIZE;  // 782
    const int NB2 = (N + HB - 1) / HB;        // 1563 node half-blocks
    const int NG  = NB * 2;                   // 1564 gather blocks

    // ws layout (4B units): cur[NBMAX] | dis[N] | off[NBMAX2*(HB+1)] | sp[NB*CAP] |
    //                       srt2[NBMAX2*HCAP] | hp(half)[16N] | gp[2N]   (~35 MB)
    int*    cur  = (int*)d_ws;
    float*  dis  = (float*)(cur + NBMAX);
    int*    off  = (int*)(dis + N);
    int*    sp   = off + (size_t)NBMAX2 * (HB + 1);
    int*    srt2 = sp + (size_t)NBMAX * CAP;
    __half* hp   = (__half*)(srt2 + (size_t)NBMAX2 * HCAP);
    float*  gp   = (float*)(hp + (size_t)N * 16);

    hipMemsetAsync(cur, 0, NBMAX * 4, stream);
    place_kernel<<<(E + CHUNK - 1) / CHUNK, PB, 0, stream>>>(row, col, cur, sp, E, NB);
    xw1_kernel  <<<NB2, 256, 0, stream>>>(x, W1, sp, cur, dis, hp, N);
    bsg1_kernel <<<NG, 256, 0, stream>>>(sp, cur, dis, (const __half2*)hp, b1, W2, srt2, off, gp, N);
    g2_kernel   <<<(int)(((size_t)N * 8 + 255) / 256), 256, 0, stream>>>(srt2, off, dis, gp, b2, out, N);
}

// Round 12
// 199.975 us; speedup vs baseline: 1.0588x; 1.0588x over previous
//
#include <hip/hip_runtime.h>
#include <hip/hip_fp16.h>

#define DIN 128
#define BSH 7                 // log2(targets per bucket)
#define BSIZE 128             // targets per bucket (place granularity)
#define HB 64                 // targets per half-bucket (gather granularity)
#define NBMAX 800             // max bucket count
#define NBMAX2 1600           // max half-bucket count
#define CAP 4480              // slots per bucket region (mean 4096 + 6 sigma)
#define HCAP 2560             // slots per half-bucket srt2 region (mean 2048 + 11 sigma)
#define CHUNK 8192            // edges per place-WG
#define PB 512                // place block size

// ---------- K1: bucket the edges (LDS-staged, coalesced run writes) ----------
__global__ __launch_bounds__(PB) void place_kernel(const int* __restrict__ row,
                                                   const int* __restrict__ col,
                                                   int* __restrict__ cur,
                                                   int* __restrict__ sp, int E, int NB) {
    __shared__ int pk[CHUNK];
    __shared__ unsigned short bkid[CHUNK];
    __shared__ int lcnt[NBMAX], lstart[NBMAX], gofs[NBMAX], lcur[NBMAX];
    __shared__ int sst[PB];
    int t = threadIdx.x;
    int e0 = blockIdx.x * CHUNK;
    int cnt = min(CHUNK, E - e0);

    for (int i = t; i < NBMAX; i += PB) { lcnt[i] = 0; lcur[i] = 0; }
    __syncthreads();
    for (int i = t; i < cnt; i += PB)
        atomicAdd(&lcnt[col[e0 + i] >> BSH], 1);
    __syncthreads();
    int b2i = t * 2;
    int v0 = (b2i + 0 < NBMAX) ? lcnt[b2i + 0] : 0;
    int v1 = (b2i + 1 < NBMAX) ? lcnt[b2i + 1] : 0;
    int tot = v0 + v1;
    sst[t] = tot;
    __syncthreads();
    for (int d = 1; d < PB; d <<= 1) {
        int tmp = (t >= d) ? sst[t - d] : 0;
        __syncthreads();
        sst[t] += tmp;
        __syncthreads();
    }
    int ex = sst[t] - tot;
    if (b2i + 0 < NBMAX) lstart[b2i + 0] = ex;
    if (b2i + 1 < NBMAX) lstart[b2i + 1] = ex + v0;
    __syncthreads();
    for (int b = t; b < NB; b += PB) {
        int c = lcnt[b];
        int gb = c ? atomicAdd(&cur[b], c) : 0;
        gofs[b] = b * CAP + gb - lstart[b];
    }
    __syncthreads();
    for (int i = t; i < cnt; i += PB) {
        int r  = row[e0 + i];
        int cc = col[e0 + i];
        int b  = cc >> BSH;
        int rk = atomicAdd(&lcur[b], 1);
        int pos = lstart[b] + rk;
        pk[pos]   = ((cc & (BSIZE - 1)) << 17) | r;
        bkid[pos] = (unsigned short)b;
    }
    __syncthreads();
    for (int i = t; i < cnt; i += PB)
        sp[gofs[bkid[i]] + i] = pk[i];
}

// ---------- K2: per-bucket degree -> dis (int4 loads) ----------
__global__ __launch_bounds__(256) void bdeg_kernel(const int* __restrict__ sp,
                                                   const int* __restrict__ cur,
                                                   float* __restrict__ dis, int N) {
    __shared__ int lcnt[BSIZE];
    int b = blockIdx.x;
    int t = threadIdx.x;
    int cntb = cur[b];
    const int* src = sp + (size_t)b * CAP;
    if (t < BSIZE) lcnt[t] = 0;
    __syncthreads();
    int n4 = cntb >> 2;
    const int4* src4 = (const int4*)src;
    for (int i = t; i < n4; i += 256) {
        int4 v = src4[i];
        atomicAdd(&lcnt[v.x >> 17], 1);
        atomicAdd(&lcnt[v.y >> 17], 1);
        atomicAdd(&lcnt[v.z >> 17], 1);
        atomicAdd(&lcnt[v.w >> 17], 1);
    }
    for (int i = (n4 << 2) + t; i < cntb; i += 256)
        atomicAdd(&lcnt[src[i] >> 17], 1);
    __syncthreads();
    if (t < BSIZE) {
        int gt = b * BSIZE + t;
        if (gt < N) dis[gt] = rsqrtf((float)lcnt[t] + 1.0f);
    }
}

// ---------- K3: hp = fp16( (x @ W1) * dis[n] ) — 2x2 blocked, float4 LDS ----------
__global__ __launch_bounds__(256) void xw1_kernel(const float* __restrict__ x,
                                                  const float* __restrict__ W1,
                                                  const float* __restrict__ dis,
                                                  __half* __restrict__ hp, int N) {
    __shared__ float xs[64 * 132];
    __shared__ float wt[16 * 132];
    int t = threadIdx.x;
    int base = blockIdx.x * 64;
    for (int i = t; i < DIN * 16; i += 256) {
        int d = i >> 4, k = i & 15;
        wt[k * 132 + d] = W1[i];
    }
    int nrow = min(64, N - base);
    for (int i = t; i < 64 * 32; i += 256) {
        int r = i >> 5, c4 = i & 31;
        float4 v = make_float4(0.f, 0.f, 0.f, 0.f);
        if (r < nrow) v = *(const float4*)(x + (size_t)(base + r) * DIN + c4 * 4);
        *(float4*)(xs + r * 132 + c4 * 4) = v;
    }
    __syncthreads();
    int np = t >> 3;
    int kp = t & 7;
    int n0 = np * 2, k0 = kp * 2;
    const float4* xa = (const float4*)(xs + n0 * 132);
    const float4* xb = (const float4*)(xs + (n0 + 1) * 132);
    const float4* wa = (const float4*)(wt + k0 * 132);
    const float4* wb = (const float4*)(wt + (k0 + 1) * 132);
    float a00 = 0.f, a01 = 0.f, a10 = 0.f, a11 = 0.f;
    #pragma unroll 8
    for (int d4 = 0; d4 < 32; d4++) {
        float4 va = xa[d4], vb = xb[d4], u0 = wa[d4], u1 = wb[d4];
        a00 += va.x*u0.x + va.y*u0.y + va.z*u0.z + va.w*u0.w;
        a01 += va.x*u1.x + va.y*u1.y + va.z*u1.z + va.w*u1.w;
        a10 += vb.x*u0.x + vb.y*u0.y + vb.z*u0.z + vb.w*u0.w;
        a11 += vb.x*u1.x + vb.y*u1.y + vb.z*u1.z + vb.w*u1.w;
    }
    int n = base + n0;
    if (n < N) {
        float d = dis[n];
        hp[(size_t)n * 16 + k0 + 0] = __float2half(a00 * d);
        hp[(size_t)n * 16 + k0 + 1] = __float2half(a01 * d);
    }
    n++;
    if (n < N) {
        float d = dis[n];
        hp[(size_t)n * 16 + k0 + 0] = __float2half(a10 * d);
        hp[(size_t)n * 16 + k0 + 1] = __float2half(a11 * d);
    }
}

// ---------- K4: per-half-bucket sort + gather1 + relu/b1/@W2/*dis -> gp, srt2, off ----------
__global__ __launch_bounds__(256) void bsg1_kernel(const int* __restrict__ sp,
                                                   const int* __restrict__ cur,
                                                   const float* __restrict__ dis,
                                                   const __half2* __restrict__ hp2,
                                                   const float* __restrict__ b1,
                                                   const float* __restrict__ W2,
                                                   int* __restrict__ srt2,
                                                   int* __restrict__ off,
                                                   float* __restrict__ gp, int N) {
    __shared__ int ss[HCAP];
    __shared__ int lcnt[HB], lstart[HB], lcur[HB], sc[HB];
    int b2 = blockIdx.x;
    int B = b2 >> 1, h = b2 & 1;
    int t = threadIdx.x;
    int cntb = cur[B];
    const int* reg = sp + (size_t)B * CAP;
    if (t < HB) { lcnt[t] = 0; lcur[t] = 0; }
    __syncthreads();
    // pass 1: count this half's targets
    for (int i = t; i < cntb; i += 256) {
        int lc = reg[i] >> 17;
        if ((lc >> 6) == h) atomicAdd(&lcnt[lc & 63], 1);
    }
    __syncthreads();
    int v = (t < HB) ? lcnt[t] : 0;
    if (t < HB) sc[t] = v;
    __syncthreads();
    for (int d = 1; d < HB; d <<= 1) {
        int tmp = (t < HB && t >= d) ? sc[t - d] : 0;
        __syncthreads();
        if (t < HB) sc[t] += tmp;
        __syncthreads();
    }
    if (t < HB) lstart[t] = sc[t] - v;
    __syncthreads();
    // pass 2: place (region is L2-hot from pass 1)
    for (int i = t; i < cntb; i += 256) {
        int vv = reg[i];
        int lc = vv >> 17;
        if ((lc >> 6) == h) {
            int l = lc & 63;
            int rk = atomicAdd(&lcur[l], 1);
            ss[lstart[l] + rk] = vv & 0x1FFFF;
        }
    }
    __syncthreads();
    int hcnt = sc[HB - 1];
    // write back sorted half + off (coalesced)
    for (int i = t; i < hcnt; i += 256) srt2[(size_t)b2 * HCAP + i] = ss[i];
    if (t < HB) {
        off[b2 * (HB + 1) + t] = b2 * HCAP + lstart[t];
    } else if (t == HB) {
        off[b2 * (HB + 1) + HB] = b2 * HCAP + hcnt;
    }
    // gather + epilogue: 2 rounds of 32 targets x 8 lanes; 4-way ILP
    int k2  = t & 7;
    int ltg = t >> 3;
    #pragma unroll
    for (int r2 = 0; r2 < 2; r2++) {
        int lt = r2 * 32 + ltg;
        int gt = B * BSIZE + h * HB + lt;
        if (gt < N) {
            int j0 = lstart[lt];
            int j1 = j0 + lcnt[lt];
            float2 acc0 = __half22float2(hp2[(size_t)gt * 8 + k2]);  // self-loop
            float2 acc1 = make_float2(0.f, 0.f);
            float2 acc2 = make_float2(0.f, 0.f);
            float2 acc3 = make_float2(0.f, 0.f);
            int j = j0;
            for (; j + 3 < j1; j += 4) {
                int r0 = ss[j + 0], r1 = ss[j + 1], r2i = ss[j + 2], r3 = ss[j + 3];
                float2 h0 = __half22float2(hp2[(size_t)r0 * 8 + k2]);
                float2 h1 = __half22float2(hp2[(size_t)r1 * 8 + k2]);
                float2 h2 = __half22float2(hp2[(size_t)r2i * 8 + k2]);
                float2 h3 = __half22float2(hp2[(size_t)r3 * 8 + k2]);
                acc0.x += h0.x; acc0.y += h0.y;
                acc1.x += h1.x; acc1.y += h1.y;
                acc2.x += h2.x; acc2.y += h2.y;
                acc3.x += h3.x; acc3.y += h3.y;
            }
            for (; j < j1; j++) {
                int r = ss[j];
                float2 hv = __half22float2(hp2[(size_t)r * 8 + k2]);
                acc0.x += hv.x; acc0.y += hv.y;
            }
            float2 acc = make_float2(acc0.x + acc1.x + acc2.x + acc3.x,
                                     acc0.y + acc1.y + acc2.y + acc3.y);
            float d = dis[gt];
            int k0 = k2 * 2;
            float v0 = fmaxf(fmaf(acc.x, d, b1[k0 + 0]), 0.0f);
            float v1 = fmaxf(fmaf(acc.y, d, b1[k0 + 1]), 0.0f);
            float p0 = v0 * W2[k0 * 2 + 0] + v1 * W2[k0 * 2 + 2];
            float p1 = v0 * W2[k0 * 2 + 1] + v1 * W2[k0 * 2 + 3];
            p0 += __shfl_xor(p0, 1); p1 += __shfl_xor(p1, 1);
            p0 += __shfl_xor(p0, 2); p1 += __shfl_xor(p1, 2);
            p0 += __shfl_xor(p0, 4); p1 += __shfl_xor(p1, 4);
            if (k2 == 0) *(float2*)(gp + (size_t)gt * 2) = make_float2(p0 * d, p1 * d);
        }
    }
}

// ---------- K5: gather-2 over srt2 (8 lanes/target) + bias + log_softmax ----------
__global__ __launch_bounds__(256) void g2_kernel(const int* __restrict__ srt2,
                                                 const int* __restrict__ off,
                                                 const float* __restrict__ dis,
                                                 const float* __restrict__ gp,
                                                 const float* __restrict__ b2,
                                                 float* __restrict__ out, int N) {
    int t = blockIdx.x * 256 + threadIdx.x;
    int c    = t >> 3;
    int slot = t & 7;
    if (c >= N) return;
    int idx = (c >> 6) * (HB + 1) + (c & 63);
    int j0 = off[idx];
    int j1 = off[idx + 1];
    float a0 = 0.0f, a1v = 0.0f;
    for (int j = j0 + slot; j < j1; j += 8) {
        int r = srt2[j];
        float2 gv = *(const float2*)(gp + (size_t)r * 2);
        a0  += gv.x;
        a1v += gv.y;
    }
    a0 += __shfl_xor(a0, 1); a1v += __shfl_xor(a1v, 1);
    a0 += __shfl_xor(a0, 2); a1v += __shfl_xor(a1v, 2);
    a0 += __shfl_xor(a0, 4); a1v += __shfl_xor(a1v, 4);
    if (slot == 0) {
        float2 self = *(const float2*)(gp + (size_t)c * 2);
        float d = dis[c];
        float o0 = (a0  + self.x) * d + b2[0];
        float o1 = (a1v + self.y) * d + b2[1];
        float m = fmaxf(o0, o1);
        float lse = m + logf(expf(o0 - m) + expf(o1 - m));
        *(float2*)(out + (size_t)c * 2) = make_float2(o0 - lse, o1 - lse);
    }
}

extern "C" void kernel_launch(void* const* d_in, const int* in_sizes, int n_in,
                              void* d_out, int out_size, void* d_ws, size_t ws_size,
                              hipStream_t stream) {
    const float* x  = (const float*)d_in[0];
    const int*   ei = (const int*)d_in[1];
    const float* W1 = (const float*)d_in[2];
    const float* b1 = (const float*)d_in[3];
    const float* W2 = (const float*)d_in[4];
    const float* b2 = (const float*)d_in[5];
    float* out = (float*)d_out;

    const int N = in_sizes[0] / DIN;          // 100000
    const int E = in_sizes[1] / 2;            // 3200000
    const int* row = ei;                      // sources
    const int* col = ei + E;                  // targets
    const int NB  = (N + BSIZE - 1) / BSIZE;  // 782
    const int NB2 = (N + HB - 1) / HB;        // 1563 node half-blocks
    const int NG  = NB * 2;                   // 1564 gather blocks

    // ws layout (4B units): cur[NBMAX] | dis[N] | off[NBMAX2*(HB+1)] | sp[NB*CAP] |
    //                       srt2[NBMAX2*HCAP] | hp(half)[16N] | gp[2N]   (~35 MB)
    int*    cur  = (int*)d_ws;
    float*  dis  = (float*)(cur + NBMAX);
    int*    off  = (int*)(dis + N);
    int*    sp   = off + (size_t)NBMAX2 * (HB + 1);
    int*    srt2 = sp + (size_t)NBMAX * CAP;
    __half* hp   = (__half*)(srt2 + (size_t)NBMAX2 * HCAP);
    float*  gp   = (float*)(hp + (size_t)N * 16);

    hipMemsetAsync(cur, 0, NBMAX * 4, stream);
    place_kernel<<<(E + CHUNK - 1) / CHUNK, PB, 0, stream>>>(row, col, cur, sp, E, NB);
    bdeg_kernel <<<NB, 256, 0, stream>>>(sp, cur, dis, N);
    xw1_kernel  <<<NB2, 256, 0, stream>>>(x, W1, dis, hp, N);
    bsg1_kernel <<<NG, 256, 0, stream>>>(sp, cur, dis, (const __half2*)hp, b1, W2, srt2, off, gp, N);
    g2_kernel   <<<(int)(((size_t)N * 8 + 255) / 256), 256, 0, stream>>>(srt2, off, dis, gp, b2, out, N);
}